// Round 12
// baseline (266.334 us; speedup 1.0000x reference)
//
#include <hip/hip_runtime.h>
#include <math.h>

#define F 1024
#define BM 128
#define BN 128
#define BK 16

typedef _Float16 h2 __attribute__((ext_vector_type(2)));
typedef _Float16 h4 __attribute__((ext_vector_type(4)));
typedef _Float16 h8 __attribute__((ext_vector_type(8)));
typedef float v4f __attribute__((ext_vector_type(4)));

#define SHUF2(v, i, j) __builtin_shufflevector(v, v, i, j)

// f32 = f16 + f16 in one full-rate op: v_fma_mix_f32(a, 1.0, b).
// op_sel picks the half of each f16 source; op_sel_hi marks srcs 0,2 as f16.
static __device__ __forceinline__ float mix_ll(h2 a, h2 b) {
  float d;
  asm("v_fma_mix_f32 %0, %1, 1.0, %2 op_sel:[0,0,0] op_sel_hi:[1,0,1]"
      : "=v"(d) : "v"(a), "v"(b));
  return d;
}
static __device__ __forceinline__ float mix_lh(h2 a, h2 b) {
  float d;
  asm("v_fma_mix_f32 %0, %1, 1.0, %2 op_sel:[0,0,1] op_sel_hi:[1,0,1]"
      : "=v"(d) : "v"(a), "v"(b));
  return d;
}
static __device__ __forceinline__ float mix_hl(h2 a, h2 b) {
  float d;
  asm("v_fma_mix_f32 %0, %1, 1.0, %2 op_sel:[1,0,0] op_sel_hi:[1,0,1]"
      : "=v"(d) : "v"(a), "v"(b));
  return d;
}
static __device__ __forceinline__ float mix_hh(h2 a, h2 b) {
  float d;
  asm("v_fma_mix_f32 %0, %1, 1.0, %2 op_sel:[1,0,1] op_sel_hi:[1,0,1]"
      : "=v"(d) : "v"(a), "v"(b));
  return d;
}
static __device__ __forceinline__ float fmax3(float a, float b, float c) {
  float d;
  asm("v_max3_f32 %0, %1, %2, %3" : "=v"(d) : "v"(a), "v"(b), "v"(c));
  return d;
}
static __device__ __forceinline__ h2 pk_max(h2 a, h2 b) {
  h2 d;
  asm("v_pk_max_f16 %0, %1, %2" : "=v"(d) : "v"(a), "v"(b));
  return d;
}

// ------- LayerNorm (one wave per row, f32 compute, fp16 out) + fused W cvt (R9-proven) -------
__global__ __launch_bounds__(256) void ln_cvt_kernel(const float* __restrict__ x,
                                                     const float* __restrict__ gamma,
                                                     const float* __restrict__ beta,
                                                     const float* __restrict__ Wm,
                                                     _Float16* __restrict__ xnh,
                                                     _Float16* __restrict__ Wh) {
  const int lane = threadIdx.x & 63;
  const int wv = threadIdx.x >> 6;
  const int row = blockIdx.x * 4 + wv;
  const float4* xr = (const float4*)(x + (size_t)row * F);
  float4 v[4];
  float s = 0.f;
#pragma unroll
  for (int j = 0; j < 4; ++j) {
    v[j] = xr[lane + 64 * j];
    s += v[j].x + v[j].y + v[j].z + v[j].w;
  }
#pragma unroll
  for (int off = 32; off; off >>= 1) s += __shfl_xor(s, off, 64);
  const float mu = s * (1.0f / F);
  float sq = 0.f;
#pragma unroll
  for (int j = 0; j < 4; ++j) {
    v[j].x -= mu; v[j].y -= mu; v[j].z -= mu; v[j].w -= mu;
    sq += v[j].x * v[j].x + v[j].y * v[j].y + v[j].z * v[j].z + v[j].w * v[j].w;
  }
#pragma unroll
  for (int off = 32; off; off >>= 1) sq += __shfl_xor(sq, off, 64);
  const float r = rsqrtf(sq * (1.0f / F) + 1e-5f);
  const float4* g4 = (const float4*)gamma;
  const float4* b4 = (const float4*)beta;
  h4* o = (h4*)(xnh + (size_t)row * F);
#pragma unroll
  for (int j = 0; j < 4; ++j) {
    const int idx = lane + 64 * j;
    const float4 g = g4[idx];
    const float4 bb = b4[idx];
    h4 ov = {(_Float16)(v[j].x * r * g.x + bb.x),
             (_Float16)(v[j].y * r * g.y + bb.y),
             (_Float16)(v[j].z * r * g.z + bb.z),
             (_Float16)(v[j].w * r * g.w + bb.w)};
    o[idx] = ov;
  }
  // fused: convert W row blockIdx.x (1024 f32) -> fp16
  {
    const int i = (int)blockIdx.x * 256 + threadIdx.x;
    const v4f wv4 = ((const v4f*)Wm)[i];
    h4 wo = {(_Float16)wv4.x, (_Float16)wv4.y, (_Float16)wv4.z, (_Float16)wv4.w};
    ((h4*)Wh)[i] = wo;
  }
}

// -------- tropical (max,+) GEMM: fp16 LDS, f32 compute via v_fma_mix --------
// Thread (tx,ty): rows 8ty..+7, cols {4tx..+3} u {64+4tx..+3}.
// Per 2 updates: 2x fma_mix (2cyc) + 1x max3 (2cyc) = 3 cyc/update; LDS 0.5B/update.
__global__ __launch_bounds__(256, 4) void trop_m(const _Float16* __restrict__ A,
                                                 const _Float16* __restrict__ Wh,
                                                 const float* __restrict__ bias,
                                                 _Float16* __restrict__ dsth,
                                                 float* __restrict__ outf,
                                                 int ntiles, int totrows, int fuse) {
  __shared__ _Float16 As[2][BK][BM + 8];  // [k][m], row stride 272 B
  __shared__ _Float16 Bs[2][BK][BN];      // [k][n], row stride 256 B

  const int tid = threadIdx.x;
  const int tx = tid & 15;
  const int ty = tid >> 4;
  const int row0 = blockIdx.y * BM;
  const int col0 = blockIdx.x * BN;
  const int kbase = blockIdx.z * ntiles * BK;

  const int ar = tid >> 1;         // A stage: row 0..127
  const int akj = (tid & 1) * 8;   // k offset 0 or 8
  const int bkr = tid >> 4;        // B stage: k-row 0..15
  const int bcg = (tid & 15) * 8;  // col group

  const _Float16* Asrc = A + (size_t)(row0 + ar) * F + kbase + akj;
  const _Float16* Bsrc = Wh + (size_t)(kbase + bkr) * F + col0 + bcg;

  float acc[8][8];
#pragma unroll
  for (int m = 0; m < 8; ++m)
#pragma unroll
    for (int n = 0; n < 8; ++n) acc[m][n] = -INFINITY;

  // stage tile 0 into buf 0
  {
    const h8 a_st = *(const h8*)Asrc;
    const h8 b_st = *(const h8*)Bsrc;
#pragma unroll
    for (int j = 0; j < 8; ++j) As[0][akj + j][ar] = a_st[j];
    *(h8*)&Bs[0][bkr][bcg] = b_st;
  }
  __syncthreads();

  for (int kt = 0; kt < ntiles; ++kt) {
    const int cur = kt & 1;
    h8 a_st, b_st;
    if (kt + 1 < ntiles) {
      a_st = *(const h8*)(Asrc + (kt + 1) * BK);
      b_st = *(const h8*)(Bsrc + (size_t)(kt + 1) * BK * F);
    }

#pragma unroll
    for (int k = 0; k < BK; k += 2) {
      union { h8 v; h2 p[4]; } a0u, a1u;
      a0u.v = *(const h8*)&As[cur][k][ty * 8];      // a_k for 8 m
      a1u.v = *(const h8*)&As[cur][k + 1][ty * 8];  // a_k1 for 8 m
      const h4 b0a = *(const h4*)&Bs[cur][k][tx * 4];
      const h4 b0b = *(const h4*)&Bs[cur][k][64 + tx * 4];
      const h4 b1a = *(const h4*)&Bs[cur][k + 1][tx * 4];
      const h4 b1b = *(const h4*)&Bs[cur][k + 1][64 + tx * 4];
      h2 b0[4], b1[4];
      b0[0] = SHUF2(b0a, 0, 1); b0[1] = SHUF2(b0a, 2, 3);
      b0[2] = SHUF2(b0b, 0, 1); b0[3] = SHUF2(b0b, 2, 3);
      b1[0] = SHUF2(b1a, 0, 1); b1[1] = SHUF2(b1a, 2, 3);
      b1[2] = SHUF2(b1b, 0, 1); b1[3] = SHUF2(b1b, 2, 3);
#pragma unroll
      for (int mp = 0; mp < 4; ++mp) {
        const h2 a0p = a0u.p[mp];
        const h2 a1p = a1u.p[mp];
#pragma unroll
        for (int q = 0; q < 4; ++q) {
          // m = 2mp (lo half of a-pair)
          const float t00 = mix_ll(a0p, b0[q]);  // (k,   n)
          const float t01 = mix_lh(a0p, b0[q]);  // (k,   n+1)
          const float t10 = mix_ll(a1p, b1[q]);  // (k+1, n)
          const float t11 = mix_lh(a1p, b1[q]);  // (k+1, n+1)
          acc[2 * mp][2 * q]     = fmax3(acc[2 * mp][2 * q], t00, t10);
          acc[2 * mp][2 * q + 1] = fmax3(acc[2 * mp][2 * q + 1], t01, t11);
          // m = 2mp+1 (hi half)
          const float u00 = mix_hl(a0p, b0[q]);
          const float u01 = mix_hh(a0p, b0[q]);
          const float u10 = mix_hl(a1p, b1[q]);
          const float u11 = mix_hh(a1p, b1[q]);
          acc[2 * mp + 1][2 * q]     = fmax3(acc[2 * mp + 1][2 * q], u00, u10);
          acc[2 * mp + 1][2 * q + 1] = fmax3(acc[2 * mp + 1][2 * q + 1], u01, u11);
        }
      }
    }

    if (kt + 1 < ntiles) {
      const int nxt = cur ^ 1;
#pragma unroll
      for (int j = 0; j < 8; ++j) As[nxt][akj + j][ar] = a_st[j];
      *(h8*)&Bs[nxt][bkr][bcg] = b_st;
      __syncthreads();
    }
  }

  if (fuse) {
    const float4 bv0 = *(const float4*)(bias + col0 + tx * 4);
    const float4 bv1 = *(const float4*)(bias + col0 + 64 + tx * 4);
#pragma unroll
    for (int m = 0; m < 8; ++m) {
      float* orow = outf + (size_t)(row0 + ty * 8 + m) * F + col0 + tx * 4;
      float4 o0, o1;
      o0.x = fmaxf(acc[m][0], bv0.x);
      o0.y = fmaxf(acc[m][1], bv0.y);
      o0.z = fmaxf(acc[m][2], bv0.z);
      o0.w = fmaxf(acc[m][3], bv0.w);
      o1.x = fmaxf(acc[m][4], bv1.x);
      o1.y = fmaxf(acc[m][5], bv1.y);
      o1.z = fmaxf(acc[m][6], bv1.z);
      o1.w = fmaxf(acc[m][7], bv1.w);
      *(float4*)orow = o0;
      *(float4*)(orow + 64) = o1;
    }
  } else {
    _Float16* base = dsth + (size_t)blockIdx.z * totrows * F;
#pragma unroll
    for (int m = 0; m < 8; ++m) {
      _Float16* orow = base + (size_t)(row0 + ty * 8 + m) * F + col0 + tx * 4;
      h4 o0 = {(_Float16)acc[m][0], (_Float16)acc[m][1],
               (_Float16)acc[m][2], (_Float16)acc[m][3]};
      h4 o1 = {(_Float16)acc[m][4], (_Float16)acc[m][5],
               (_Float16)acc[m][6], (_Float16)acc[m][7]};
      *(h4*)orow = o0;
      *(h4*)(orow + 64) = o1;
    }
  }
}

// ---------------- combine: out = max(NP fp16 partials, bias) in f32 ----------------
template <int NP>
__global__ __launch_bounds__(256) void combineNh(const _Float16* __restrict__ p,
                                                 size_t plane,
                                                 const float* __restrict__ bias,
                                                 float* __restrict__ out) {
  const int i = blockIdx.x * 256 + threadIdx.x;  // h8 index
  h8 v = ((const h8*)p)[i];
  h2* vv = (h2*)&v;
#pragma unroll
  for (int q = 1; q < NP; ++q) {
    const h8 u = ((const h8*)(p + (size_t)q * plane))[i];
    const h2* uu = (const h2*)&u;
#pragma unroll
    for (int j = 0; j < 4; ++j) vv[j] = pk_max(vv[j], uu[j]);
  }
  const int nb = (i & (F / 8 - 1)) * 8;
  const v4f bb0 = *(const v4f*)(bias + nb);
  const v4f bb1 = *(const v4f*)(bias + nb + 4);
  float4* o4 = (float4*)(out + (size_t)i * 8);
  float4 o0, o1;
  o0.x = fmaxf((float)v[0], bb0.x);
  o0.y = fmaxf((float)v[1], bb0.y);
  o0.z = fmaxf((float)v[2], bb0.z);
  o0.w = fmaxf((float)v[3], bb0.w);
  o1.x = fmaxf((float)v[4], bb1.x);
  o1.y = fmaxf((float)v[5], bb1.y);
  o1.z = fmaxf((float)v[6], bb1.z);
  o1.w = fmaxf((float)v[7], bb1.w);
  o4[0] = o0;
  o4[1] = o1;
}

extern "C" void kernel_launch(void* const* d_in, const int* in_sizes, int n_in,
                              void* d_out, int out_size, void* d_ws, size_t ws_size,
                              hipStream_t stream) {
  const float* x = (const float*)d_in[0];
  const float* Wm = (const float*)d_in[1];
  const float* bias = (const float*)d_in[2];
  const float* gamma = (const float*)d_in[3];
  const float* beta = (const float*)d_in[4];
  float* out = (float*)d_out;

  const int Brows = in_sizes[0] / F;  // 4096
  const size_t plane = (size_t)Brows * F;

  _Float16* xnh = (_Float16*)d_ws;       // plane fp16 (8 MB)
  _Float16* Wh = xnh + plane;            // F*F fp16 (2 MB)
  _Float16* parts = Wh + (size_t)F * F;  // 4 planes fp16 (32 MB)

  ln_cvt_kernel<<<Brows / 4, 256, 0, stream>>>(x, gamma, beta, Wm, xnh, Wh);

  const size_t need4 = (5 * plane + (size_t)F * F) * sizeof(_Float16);
  const size_t need1 = (plane + (size_t)F * F) * sizeof(_Float16);
  if (ws_size >= need4) {
    dim3 grid(F / BN, Brows / BM, 4);  // 1024 blocks = 4 blocks/CU
    trop_m<<<grid, 256, 0, stream>>>(xnh, Wh, bias, parts, nullptr,
                                     (F / BK) / 4, Brows, 0);
    combineNh<4><<<(int)(plane / 2048), 256, 0, stream>>>(parts, plane, bias, out);
  } else if (ws_size >= need1) {
    dim3 grid(F / BN, Brows / BM, 1);
    trop_m<<<grid, 256, 0, stream>>>(xnh, Wh, bias, nullptr, out, F / BK, Brows, 1);
  }
}